// Round 1
// 389.138 us; speedup vs baseline: 1.0876x; 1.0876x over previous
//
#include <hip/hip_runtime.h>

typedef unsigned short u16;
typedef unsigned int u32;
typedef __attribute__((ext_vector_type(8))) short short8v;
typedef __attribute__((ext_vector_type(4))) short short4v;
typedef __attribute__((ext_vector_type(4))) float floatx4;

#define BB 4
#define SS 2048
#define DD 1024
#define HH 16
#define DKK 64
#define MM (BB * SS)   // 8192
#define KK DD
#define NN DD
// log2(e)/sqrt(DK): folded into Q projection so scores feed exp2 directly
#define QSCALE 0.18033688011112042f

// Ps padded layout (r3-verified conflict-free): row stride 12 u16, chunk stride 200 u16
#define PS_RS 12
#define PS_CS 200
#define PS_REGION 1600  // 8 chunks of 8 keys x 16 q rows

__device__ __forceinline__ u16 f2bf(float f) {
  union { __bf16 h; u16 u; } r; r.h = (__bf16)f; return r.u;
}
__device__ __forceinline__ u32 pack2bf(float a, float b) {
  union { u32 u; __bf16 h[2]; } r;
  r.h[0] = (__bf16)a; r.h[1] = (__bf16)b; return r.u;
}
__device__ __forceinline__ short8v cat44(short4v a, short4v b) {
  return __builtin_shufflevector(a, b, 0, 1, 2, 3, 4, 5, 6, 7);
}

__device__ __forceinline__ void load_lds16(const void* g, void* l) {
  __builtin_amdgcn_global_load_lds((const __attribute__((address_space(1))) void*)g,
                                   (__attribute__((address_space(3))) void*)l, 16, 0, 0);
}

__device__ __forceinline__ floatx4 mfma_k32(short8v a, short8v b, floatx4 c) {
  return __builtin_amdgcn_mfma_f32_16x16x32_bf16(a, b, c, 0, 0, 0);
}

// ---------------- fp32 -> bf16 converts (fused launches) ----------------
__global__ __launch_bounds__(256) void cvt_w4(const float* __restrict__ w0,
                                              const float* __restrict__ w1,
                                              const float* __restrict__ w2,
                                              const float* __restrict__ w3,
                                              u16* __restrict__ out) {
  const int y = blockIdx.y;
  const float* in = (y == 0) ? w0 : (y == 1) ? w1 : (y == 2) ? w2 : w3;
  u16* o = out + (size_t)y * DD * DD;
  const int i = (blockIdx.x * 256 + threadIdx.x) * 8;
  float4 a = *(const float4*)(in + i);
  float4 b = *(const float4*)(in + i + 4);
  uint4 v;
  v.x = pack2bf(a.x, a.y); v.y = pack2bf(a.z, a.w);
  v.z = pack2bf(b.x, b.y); v.w = pack2bf(b.z, b.w);
  *(uint4*)(o + i) = v;
}

__global__ __launch_bounds__(256) void cvt_a3(const float* __restrict__ a0,
                                              const float* __restrict__ a1,
                                              const float* __restrict__ a2,
                                              u16* __restrict__ o0, u16* __restrict__ o1,
                                              u16* __restrict__ o2) {
  const int y = blockIdx.y;
  const float* in = (y == 0) ? a0 : (y == 1) ? a1 : a2;
  u16* o = (y == 0) ? o0 : (y == 1) ? o1 : o2;
  const int i = (blockIdx.x * 256 + threadIdx.x) * 8;
  float4 a = *(const float4*)(in + i);
  float4 b = *(const float4*)(in + i + 4);
  uint4 v;
  v.x = pack2bf(a.x, a.y); v.y = pack2bf(a.z, a.w);
  v.z = pack2bf(b.x, b.y); v.w = pack2bf(b.z, b.w);
  *(uint4*)(o + i) = v;
}

// ---------------- GEMM core: acc[4][4] = A_tile @ W_tile^T (128x128, BK=32) ----------------
// Software-pipelined: stage(k+1) issued after frag reads, overlapping the MFMAs.
__device__ __forceinline__ void gemm_tile(const u16* __restrict__ A, const u16* __restrict__ W,
                                          u16* As, u16* Bs, floatx4 (&acc)[4][4]) {
  const int tid = threadIdx.x;
  const int w = tid >> 6, lane = tid & 63;
  const int lr = lane & 15, lq = lane >> 4;
  const int wr = w >> 1, wc = w & 1;
  const u16* ga0 = A + (size_t)(2 * w * 16 + lr) * KK + lq * 8;
  const u16* ga1 = ga0 + 16 * KK;
  const u16* gb0 = W + (size_t)(2 * w * 16 + lr) * KK + lq * 8;
  const u16* gb1 = gb0 + 16 * KK;
  u16* la0 = &As[(2 * w) * 512]; u16* la1 = la0 + 512;
  u16* lb0 = &Bs[(2 * w) * 512]; u16* lb1 = lb0 + 512;

  load_lds16(ga0, la0); load_lds16(ga1, la1);
  load_lds16(gb0, lb0); load_lds16(gb1, lb1);

  for (int k0 = 0; k0 < KK; k0 += 32) {
    __syncthreads();
    short8v af[4], bf[4];
#pragma unroll
    for (int i = 0; i < 4; ++i) {
      af[i] = *(const short8v*)&As[(wr * 4 + i) * 512 + lane * 8];
      bf[i] = *(const short8v*)&Bs[(wc * 4 + i) * 512 + lane * 8];
    }
    __syncthreads();
    if (k0 + 32 < KK) {
      load_lds16(ga0 + k0 + 32, la0); load_lds16(ga1 + k0 + 32, la1);
      load_lds16(gb0 + k0 + 32, lb0); load_lds16(gb1 + k0 + 32, lb1);
    }
#pragma unroll
    for (int i = 0; i < 4; ++i)
#pragma unroll
      for (int j = 0; j < 4; ++j)
        acc[i][j] = mfma_k32(af[i], bf[j], acc[i][j]);
  }
}

// ---------------- fused QKV projection (blockIdx.z selects q/k/v) ----------------
__global__ __launch_bounds__(256) void proj_gemm(
    const u16* __restrict__ qc, const u16* __restrict__ kc, const u16* __restrict__ vc,
    const u16* __restrict__ Wq, const u16* __restrict__ Wk, const u16* __restrict__ Wv,
    const float* __restrict__ bq, const float* __restrict__ bk, const float* __restrict__ bv,
    u16* __restrict__ Qb, u16* __restrict__ Kb, u16* __restrict__ Vtb) {
  __shared__ __align__(16) u16 As[128 * 32];
  __shared__ __align__(16) u16 Bs[128 * 32];
  const int z = blockIdx.z;
  const u16* A = (z == 0) ? qc : (z == 1) ? kc : vc;
  const u16* W = (z == 0) ? Wq : (z == 1) ? Wk : Wv;
  const float* bias = (z == 0) ? bq : (z == 1) ? bk : bv;
  const int m0 = blockIdx.x * 128, n0 = blockIdx.y * 128;

  floatx4 acc[4][4] = {};
  gemm_tile(A + (size_t)m0 * KK, W + (size_t)n0 * KK, As, Bs, acc);

  const int tid = threadIdx.x;
  const int w = tid >> 6, lane = tid & 63;
  const int lr = lane & 15, lq = lane >> 4;
  const int wr = w >> 1, wc = w & 1;

  if (z == 2) {
    // V^T store [B,H,DK,S]: r=0..3 are consecutive s -> packed b64 (r3-verified)
#pragma unroll
    for (int j = 0; j < 4; ++j) {
      const int col = n0 + wc * 64 + j * 16 + lr;
      const float bv_ = bias[col];
      const int h = col >> 6, dk = col & 63;
#pragma unroll
      for (int i = 0; i < 4; ++i) {
        const int row = m0 + wr * 64 + i * 16 + lq * 4;
        const int b = row >> 11, s = row & (SS - 1);
        uint2 pk;
        pk.x = pack2bf(acc[i][j][0] + bv_, acc[i][j][1] + bv_);
        pk.y = pack2bf(acc[i][j][2] + bv_, acc[i][j][3] + bv_);
        *(uint2*)&Vtb[(((size_t)(b * HH + h)) * DKK + dk) * SS + s] = pk;
      }
    }
  } else {
    u16* out = (z == 0) ? Qb : Kb;
    const float sc = (z == 0) ? QSCALE : 1.0f;
#pragma unroll
    for (int j = 0; j < 4; ++j) {
      const int col = n0 + wc * 64 + j * 16 + lr;
      const float bv_ = bias[col];
#pragma unroll
      for (int i = 0; i < 4; ++i)
#pragma unroll
        for (int r = 0; r < 4; ++r) {
          const int row = m0 + wr * 64 + i * 16 + lq * 4 + r;
          out[(size_t)row * NN + col] = f2bf((acc[i][j][r] + bv_) * sc);
        }
    }
  }
}

// ---------------- output GEMM (fp32 store) ----------------
__global__ __launch_bounds__(256) void out_gemm(const u16* __restrict__ A,
                                                const u16* __restrict__ W,
                                                const float* __restrict__ bias,
                                                float* __restrict__ out) {
  __shared__ __align__(16) u16 As[128 * 32];
  __shared__ __align__(16) u16 Bs[128 * 32];
  const int m0 = blockIdx.x * 128, n0 = blockIdx.y * 128;
  floatx4 acc[4][4] = {};
  gemm_tile(A + (size_t)m0 * KK, W + (size_t)n0 * KK, As, Bs, acc);

  const int tid = threadIdx.x;
  const int w = tid >> 6, lane = tid & 63;
  const int lr = lane & 15, lq = lane >> 4;
  const int wr = w >> 1, wc = w & 1;
#pragma unroll
  for (int j = 0; j < 4; ++j) {
    const int col = n0 + wc * 64 + j * 16 + lr;
    const float bv = bias[col];
#pragma unroll
    for (int i = 0; i < 4; ++i)
#pragma unroll
      for (int r = 0; r < 4; ++r) {
        const int row = m0 + wr * 64 + i * 16 + lq * 4 + r;
        out[(size_t)row * NN + col] = acc[i][j][r] + bv;
      }
  }
}

// ---------------- flash attention: r2 geometry + r3 conflict-free Ps ----------------
// Non-transposed scores: S = Q·K^T via mfma(A=Q-frag, B=K-frag), D[q][key].
// P round-trips through padded Ps (LDS) to become the PV A-operand.
// 4 waves x 32 q (2 strips of 16); K-tiles of 64 keys. Grid x=bh (XCD L2 locality).
// r4: Ps is per-wave scratch read back immediately per strip -> strips share ONE
// region (DS ops are in-order per wave). LDS 41984->29184 B => 4 blocks/CU, so all
// 1024 blocks are co-resident in one dispatch round (no 256-block straggler tail).
__global__ __launch_bounds__(256, 4) void attn_kernel(const u16* __restrict__ Q,
                                                      const u16* __restrict__ Kmat,
                                                      const u16* __restrict__ Vt,
                                                      u16* __restrict__ ctx) {
  __shared__ __align__(16) u16 Ks[64 * 64];  // chunk 2t+half: key 16t+lr, dk 32*half+8lq+j
  __shared__ __align__(16) u16 Vs[64 * 64];  // chunk 2t+half: dk 16t+lr, key 32*half+8lq+j
  __shared__ __align__(16) u16 Ps[4 * PS_REGION];  // per-wave scratch (strips share)
  const int tid = threadIdx.x;
  const int w = tid >> 6, lane = tid & 63;
  const int lr = lane & 15, lq = lane >> 4;
  const int bh = blockIdx.x, b = bh >> 4, h = bh & 15;
  const int q0 = blockIdx.y * 128;

  // Q as A-operand: lane m=lr=q-in-strip, k-slot (lq, j) -> dk = 32*half + 8lq + j
  short8v qf[2][2];
  {
    const u16* qp = Q + ((size_t)(b * SS + q0 + w * 32 + lr)) * DD + h * 64 + lq * 8;
    qf[0][0] = *(const short8v*)qp;
    qf[0][1] = *(const short8v*)(qp + 32);
    qf[1][0] = *(const short8v*)(qp + 16 * DD);
    qf[1][1] = *(const short8v*)(qp + 16 * DD + 32);
  }
  floatx4 o[2][4] = {};     // o[s][t]: row q=4lq+r, col dk=16t+lr
  float l_part[2][4] = {};  // per-lane partial denom for query row r of strip s

  const u16* kp = Kmat + ((size_t)(b * SS + w * 16 + lr)) * DD + h * 64 + lq * 8;
  const u16* vp = Vt + (((size_t)(b * HH + h)) * DKK + w * 16 + lr) * SS + lq * 8;

  for (int kt = 0; kt < SS / 64; ++kt) {
    load_lds16(kp,      &Ks[(2 * w) * 512]);
    load_lds16(kp + 32, &Ks[(2 * w + 1) * 512]);
    load_lds16(vp,      &Vs[(2 * w) * 512]);
    load_lds16(vp + 32, &Vs[(2 * w + 1) * 512]);
    kp += 64 * DD; vp += 64;
    __syncthreads();

    // S: D[row=q(4lq+r)][col=key(16t+lr)] per strip
    floatx4 sc[2][4] = {};
#pragma unroll
    for (int t = 0; t < 4; ++t) {
      short8v kb0 = *(const short8v*)&Ks[t * 1024 + lane * 8];
      short8v kb1 = *(const short8v*)&Ks[t * 1024 + 512 + lane * 8];
#pragma unroll
      for (int s = 0; s < 2; ++s) {
        sc[s][t] = mfma_k32(qf[s][0], kb0, sc[s][t]);
        sc[s][t] = mfma_k32(qf[s][1], kb1, sc[s][t]);
      }
    }

    short8v pa[2][2];
#pragma unroll
    for (int s = 0; s < 2; ++s) {
#pragma unroll
      for (int t = 0; t < 4; ++t) {
#pragma unroll
        for (int r = 0; r < 4; ++r) {
          const float e = __builtin_amdgcn_exp2f(sc[s][t][r]);
          sc[s][t][r] = e;
          l_part[s][r] += e;
        }
      }
      // write P[q][key]: chunk=key>>3, row=q, col=key&7 (padded, conflict-free)
      // strips reuse one region: strip-s reads complete (lgkmcnt-ordered, DS
      // in-order per wave) before strip-(s+1) writes land.
      u16* pw = &Ps[w * PS_REGION];
#pragma unroll
      for (int t = 0; t < 4; ++t) {
        const int base = (2 * t + (lr >> 3)) * PS_CS + (lr & 7);
#pragma unroll
        for (int r = 0; r < 4; ++r)
          pw[base + (lq * 4 + r) * PS_RS] = f2bf(sc[s][t][r]);
      }
      // read A-frag: m=q=lr, slot (lq,j) -> key 8lq+j (pa[0]) / 32+8lq+j (pa[1])
      {
        const u16* rp0 = pw + lq * PS_CS + lr * PS_RS;
        const u16* rp1 = pw + (4 + lq) * PS_CS + lr * PS_RS;
        pa[s][0] = cat44(*(const short4v*)rp0, *(const short4v*)(rp0 + 4));
        pa[s][1] = cat44(*(const short4v*)rp1, *(const short4v*)(rp1 + 4));
      }
    }

#pragma unroll
    for (int t = 0; t < 4; ++t) {
      short8v vb0 = *(const short8v*)&Vs[t * 1024 + lane * 8];
      short8v vb1 = *(const short8v*)&Vs[t * 1024 + 512 + lane * 8];
#pragma unroll
      for (int s = 0; s < 2; ++s) {
        o[s][t] = mfma_k32(pa[s][0], vb0, o[s][t]);
        o[s][t] = mfma_k32(pa[s][1], vb1, o[s][t]);
      }
    }
    __syncthreads();
  }

  float inv[2][4];
#pragma unroll
  for (int s = 0; s < 2; ++s)
#pragma unroll
    for (int r = 0; r < 4; ++r) {
      float l = l_part[s][r];
      l += __shfl_xor(l, 1); l += __shfl_xor(l, 2);
      l += __shfl_xor(l, 4); l += __shfl_xor(l, 8);
      inv[s][r] = 1.0f / l;
    }

#pragma unroll
  for (int s = 0; s < 2; ++s)
#pragma unroll
    for (int r = 0; r < 4; ++r) {
      const int sq = q0 + w * 32 + s * 16 + lq * 4 + r;
      u16* cp = ctx + ((size_t)(b * SS + sq)) * DD + h * 64;
      const float iv = inv[s][r];
#pragma unroll
      for (int t = 0; t < 4; ++t)
        cp[t * 16 + lr] = f2bf(o[s][t][r] * iv);
    }
}

// ---------------- launch ----------------
extern "C" void kernel_launch(void* const* d_in, const int* in_sizes, int n_in,
                              void* d_out, int out_size, void* d_ws, size_t ws_size,
                              hipStream_t stream) {
  const float* query = (const float*)d_in[0];
  const float* key   = (const float*)d_in[1];
  const float* value = (const float*)d_in[2];
  const float* Wq = (const float*)d_in[3];  const float* bq = (const float*)d_in[4];
  const float* Wk = (const float*)d_in[5];  const float* bk = (const float*)d_in[6];
  const float* Wv = (const float*)d_in[7];  const float* bv = (const float*)d_in[8];
  const float* Wo = (const float*)d_in[9];  const float* bo = (const float*)d_in[10];
  float* out = (float*)d_out;

  char* ws = (char*)d_ws;
  size_t off = 0;
  u16* Wb   = (u16*)(ws + off); off += (size_t)4 * DD * DD * 2;  // Wq,Wk,Wv,Wo bf16
  u16* Qb   = (u16*)(ws + off); off += (size_t)MM * DD * 2;      // scaled Q [B,S,D]
  u16* Kb   = (u16*)(ws + off); off += (size_t)MM * DD * 2;      // [B,S,D]
  u16* Vtb  = (u16*)(ws + off); off += (size_t)MM * DD * 2;      // [B,H,DK,S]
  u16* qc   = (u16*)(ws + off);
  u16* ctxb = qc;               off += (size_t)MM * DD * 2;      // ctx aliases qc
  u16* kc = (u16*)d_out;                       // scratch in d_out (overwritten last)
  u16* vc = (u16*)d_out + (size_t)MM * DD;
  u16* Wq_b = Wb, *Wk_b = Wb + (size_t)DD * DD, *Wv_b = Wb + (size_t)2 * DD * DD,
     *Wo_b = Wb + (size_t)3 * DD * DD;

  const int wn = DD * DD, an = MM * DD;
  cvt_w4<<<dim3(wn / 2048, 4), 256, 0, stream>>>(Wq, Wk, Wv, Wo, Wb);
  cvt_a3<<<dim3(an / 2048, 3), 256, 0, stream>>>(query, key, value, qc, kc, vc);

  proj_gemm<<<dim3(MM / 128, NN / 128, 3), 256, 0, stream>>>(
      qc, kc, vc, Wq_b, Wk_b, Wv_b, bq, bk, bv, Qb, Kb, Vtb);

  attn_kernel<<<dim3(BB * HH, SS / 128), 256, 0, stream>>>(Qb, Kb, Vtb, ctxb);

  out_gemm<<<dim3(MM / 128, NN / 128), 256, 0, stream>>>(ctxb, Wo_b, bo, out);
}

// Round 2
// 363.206 us; speedup vs baseline: 1.1652x; 1.0714x over previous
//
#include <hip/hip_runtime.h>

typedef unsigned short u16;
typedef unsigned int u32;
typedef __attribute__((ext_vector_type(8))) short short8v;
typedef __attribute__((ext_vector_type(4))) short short4v;
typedef __attribute__((ext_vector_type(4))) float floatx4;

#define BB 4
#define SS 2048
#define DD 1024
#define HH 16
#define DKK 64
#define MM (BB * SS)   // 8192
#define KK DD
#define NN DD
// log2(e)/sqrt(DK): folded into Q projection so scores feed exp2 directly
#define QSCALE 0.18033688011112042f

// Ps padded layout (r3-verified conflict-free): row stride 12 u16, chunk stride 200 u16
#define PS_RS 12
#define PS_CS 200
#define PS_REGION 1600

__device__ __forceinline__ u16 f2bf(float f) {
  union { __bf16 h; u16 u; } r; r.h = (__bf16)f; return r.u;
}
__device__ __forceinline__ u32 pack2bf(float a, float b) {
  union { u32 u; __bf16 h[2]; } r;
  r.h[0] = (__bf16)a; r.h[1] = (__bf16)b; return r.u;
}
__device__ __forceinline__ short8v cat44(short4v a, short4v b) {
  return __builtin_shufflevector(a, b, 0, 1, 2, 3, 4, 5, 6, 7);
}

__device__ __forceinline__ void load_lds16(const void* g, void* l) {
  __builtin_amdgcn_global_load_lds((const __attribute__((address_space(1))) void*)g,
                                   (__attribute__((address_space(3))) void*)l, 16, 0, 0);
}

__device__ __forceinline__ floatx4 mfma_k32(short8v a, short8v b, floatx4 c) {
  return __builtin_amdgcn_mfma_f32_16x16x32_bf16(a, b, c, 0, 0, 0);
}

// ---------------- fp32 -> bf16 converts (fused launches) ----------------
__global__ __launch_bounds__(256) void cvt_w4(const float* __restrict__ w0,
                                              const float* __restrict__ w1,
                                              const float* __restrict__ w2,
                                              const float* __restrict__ w3,
                                              u16* __restrict__ out) {
  const int y = blockIdx.y;
  const float* in = (y == 0) ? w0 : (y == 1) ? w1 : (y == 2) ? w2 : w3;
  u16* o = out + (size_t)y * DD * DD;
  const int i = (blockIdx.x * 256 + threadIdx.x) * 8;
  float4 a = *(const float4*)(in + i);
  float4 b = *(const float4*)(in + i + 4);
  uint4 v;
  v.x = pack2bf(a.x, a.y); v.y = pack2bf(a.z, a.w);
  v.z = pack2bf(b.x, b.y); v.w = pack2bf(b.z, b.w);
  *(uint4*)(o + i) = v;
}

__global__ __launch_bounds__(256) void cvt_a3(const float* __restrict__ a0,
                                              const float* __restrict__ a1,
                                              const float* __restrict__ a2,
                                              u16* __restrict__ o0, u16* __restrict__ o1,
                                              u16* __restrict__ o2) {
  const int y = blockIdx.y;
  const float* in = (y == 0) ? a0 : (y == 1) ? a1 : a2;
  u16* o = (y == 0) ? o0 : (y == 1) ? o1 : o2;
  const int i = (blockIdx.x * 256 + threadIdx.x) * 8;
  float4 a = *(const float4*)(in + i);
  float4 b = *(const float4*)(in + i + 4);
  uint4 v;
  v.x = pack2bf(a.x, a.y); v.y = pack2bf(a.z, a.w);
  v.z = pack2bf(b.x, b.y); v.w = pack2bf(b.z, b.w);
  *(uint4*)(o + i) = v;
}

// ================= 256x256 8-phase GEMM core (T2+T3+T4+T5) =================
// BM=BN=256, BK=64, 2 K-tiles/iteration, 8 waves (2M x 4N), per-wave 128x64.
// LDS: As/Bs each [2 dbuf][2 half][128 rows][64 k] bf16 = 64 KiB -> 128 KiB total.
// Swizzle (T2): element (r,c) stored at c' = c ^ ((r&7)<<3). 16B-group-granular,
// so global_load_lds keeps a LINEAR LDS dest and the SOURCE 16B-group is
// pre-swizzled per lane (rule #21). ds_read of a frag column then spreads the
// 16 rows across 8 distinct 16B slots -> 2-way bank aliasing (free).
// Schedule (ledger-derived; counted waits, never drain-0 in steady state):
//   iter j consumes tile e=2j (dbuf0, phases 0-3) and o=2j+1 (dbuf1, phases 4-7).
//   reads/phase: p0:12 (A fr0-3 + B fc0-1), p1:4 (B fc2-3), p2:8 (A fr4-7), p3:0.
//   stages: p0:A0(o) p1:A1(o) p2:B0(e+2) p3:B1(e+2) p4:A0(e+2) p5:A1(e+2)
//           p6:B0(o+2) p7:B1(o+2)   (each 2 x global_load_lds per thread)
//   Every stage lands >=1 barrier after the target slot's last read.
//   waits: vmcnt(4) at p3 and p7 (2 half-tiles in flight). Exact-count proof:
//   at p3 of iter j: issued 20+16j, vmcnt(4) => landed>=16+16j = A1(o). At p7:
//   issued 28+16j, landed>=24+16j = A1(e+2). Last iter: p3 uses vmcnt(0).
#define NT (KK / 64)     // 16 K-tiles
#define ITERS (NT / 2)   // 8

__device__ __forceinline__ void stage_half(const u16* __restrict__ gsrc, u16* ldst,
                                           int tid) {
#pragma unroll
  for (int L = 0; L < 2; ++L) {
    const int s = L * 512 + tid;
    const int r = s >> 3;
    const int g = (s & 7) ^ (r & 7);   // inverse-swizzled source 16B-group
    load_lds16(gsrc + (size_t)r * KK + g * 8, ldst + s * 8);
  }
}

__device__ __forceinline__ void gemm256_core(const u16* __restrict__ A,  // + m0*KK
                                             const u16* __restrict__ W,  // + n0*KK
                                             u16* As, u16* Bs,           // [2][2][8192]
                                             floatx4 (&acc)[8][4]) {
  const int tid = threadIdx.x;
  const int w = tid >> 6, lane = tid & 63;
  const int wm = w >> 2, wn = w & 3;
  const int wnh = wn >> 1, wno = wn & 1;
  const int lr = lane & 15;
  // swizzled col base for kk=0; kk=1 flips bit5 (c0 ^ 32)
  const int c0 = (((lane >> 2) & 1) << 5) | ((((lane >> 4) ^ lane) & 3) << 3);

#define AP(d, fr, kk) \
  (*(const short8v*)(As + ((d)*2 + wm) * 8192 + ((fr)*16 + lr) * 64 + (c0 ^ ((kk)*32))))
#define BP(d, fc, kk) \
  (*(const short8v*)(Bs + ((d)*2 + wnh) * 8192 + (wno * 64 + (fc)*16 + lr) * 64 + (c0 ^ ((kk)*32))))
#define MFMA8(FROFF, B, FCOFF)                                                  \
  _Pragma("unroll") for (int fr_ = 0; fr_ < 4; ++fr_)                           \
  _Pragma("unroll") for (int fc_ = 0; fc_ < 2; ++fc_) {                         \
    acc[(FROFF) + fr_][(FCOFF) + fc_] =                                         \
        mfma_k32(a[fr_][0], B[fc_][0], acc[(FROFF) + fr_][(FCOFF) + fc_]);      \
    acc[(FROFF) + fr_][(FCOFF) + fc_] =                                         \
        mfma_k32(a[fr_][1], B[fc_][1], acc[(FROFF) + fr_][(FCOFF) + fc_]);      \
  }
#define BAR() __builtin_amdgcn_s_barrier()
#define PRIO1() __builtin_amdgcn_s_setprio(1)
#define PRIO0() __builtin_amdgcn_s_setprio(0)

  short8v a[4][2], b01[2][2], b23[2][2];

  // prologue: tile0 all 4 halves + tile1 B-halves; wait first 4 halves landed
  stage_half(A, As + 0 * 8192, tid);
  stage_half(A + (size_t)128 * KK, As + 1 * 8192, tid);
  stage_half(W, Bs + 0 * 8192, tid);
  stage_half(W + (size_t)128 * KK, Bs + 1 * 8192, tid);
  stage_half(W + 64, Bs + 2 * 8192, tid);
  stage_half(W + (size_t)128 * KK + 64, Bs + 3 * 8192, tid);
  asm volatile("s_waitcnt vmcnt(4)" ::: "memory");
  BAR();

#pragma unroll 1
  for (int j = 0; j < ITERS; ++j) {
    const int e = 2 * j, o = e + 1;
    const bool haveE2 = (j + 1 < ITERS);
    // ---- phase 0: tile e reads A fr0-3 + B fc0-1; stage A0(o) -> d1 H0
#pragma unroll
    for (int fr = 0; fr < 4; ++fr) { a[fr][0] = AP(0, fr, 0); a[fr][1] = AP(0, fr, 1); }
#pragma unroll
    for (int fc = 0; fc < 2; ++fc) { b01[fc][0] = BP(0, fc, 0); b01[fc][1] = BP(0, fc, 1); }
    stage_half(A + (size_t)o * 64, As + 2 * 8192, tid);
    BAR(); PRIO1(); MFMA8(0, b01, 0); PRIO0(); BAR();
    // ---- phase 1: reads B fc2-3; stage A1(o) -> d1 H1
#pragma unroll
    for (int fc = 0; fc < 2; ++fc) { b23[fc][0] = BP(0, fc + 2, 0); b23[fc][1] = BP(0, fc + 2, 1); }
    stage_half(A + (size_t)128 * KK + (size_t)o * 64, As + 3 * 8192, tid);
    BAR(); PRIO1(); MFMA8(0, b23, 2); PRIO0(); BAR();
    // ---- phase 2: reads A fr4-7; stage B0(e+2) -> d0 H0
#pragma unroll
    for (int fr = 0; fr < 4; ++fr) { a[fr][0] = AP(0, fr + 4, 0); a[fr][1] = AP(0, fr + 4, 1); }
    if (haveE2) stage_half(W + (size_t)(e + 2) * 64, Bs + 0 * 8192, tid);
    BAR(); PRIO1(); MFMA8(4, b01, 0); PRIO0(); BAR();
    // ---- phase 3: stage B1(e+2) -> d0 H1; counted wait
    if (haveE2) {
      stage_half(W + (size_t)128 * KK + (size_t)(e + 2) * 64, Bs + 1 * 8192, tid);
      asm volatile("s_waitcnt vmcnt(4)" ::: "memory");
    } else {
      asm volatile("s_waitcnt vmcnt(0)" ::: "memory");
    }
    BAR(); PRIO1(); MFMA8(4, b23, 2); PRIO0(); BAR();
    // ---- phase 4: tile o reads A fr0-3 + B fc0-1 (d1); stage A0(e+2) -> d0 H0
#pragma unroll
    for (int fr = 0; fr < 4; ++fr) { a[fr][0] = AP(1, fr, 0); a[fr][1] = AP(1, fr, 1); }
#pragma unroll
    for (int fc = 0; fc < 2; ++fc) { b01[fc][0] = BP(1, fc, 0); b01[fc][1] = BP(1, fc, 1); }
    if (haveE2) stage_half(A + (size_t)(e + 2) * 64, As + 0 * 8192, tid);
    BAR(); PRIO1(); MFMA8(0, b01, 0); PRIO0(); BAR();
    // ---- phase 5: reads B fc2-3 (d1); stage A1(e+2) -> d0 H1
#pragma unroll
    for (int fc = 0; fc < 2; ++fc) { b23[fc][0] = BP(1, fc + 2, 0); b23[fc][1] = BP(1, fc + 2, 1); }
    if (haveE2) stage_half(A + (size_t)128 * KK + (size_t)(e + 2) * 64, As + 1 * 8192, tid);
    BAR(); PRIO1(); MFMA8(0, b23, 2); PRIO0(); BAR();
    // ---- phase 6: reads A fr4-7 (d1); stage B0(o+2) -> d1 H0
#pragma unroll
    for (int fr = 0; fr < 4; ++fr) { a[fr][0] = AP(1, fr + 4, 0); a[fr][1] = AP(1, fr + 4, 1); }
    if (haveE2) stage_half(W + (size_t)(o + 2) * 64, Bs + 2 * 8192, tid);
    BAR(); PRIO1(); MFMA8(4, b01, 0); PRIO0(); BAR();
    // ---- phase 7: stage B1(o+2) -> d1 H1; counted wait (skip entirely on last)
    if (haveE2) {
      stage_half(W + (size_t)128 * KK + (size_t)(o + 2) * 64, Bs + 3 * 8192, tid);
      asm volatile("s_waitcnt vmcnt(4)" ::: "memory");
    }
    BAR(); PRIO1(); MFMA8(4, b23, 2); PRIO0(); BAR();
  }
#undef AP
#undef BP
#undef MFMA8
#undef BAR
#undef PRIO1
#undef PRIO0
}

// ---------------- fused QKV projection (blockIdx.z selects q/k/v) ----------------
__global__ __launch_bounds__(512, 2) void proj_gemm(
    const u16* __restrict__ qc, const u16* __restrict__ kc, const u16* __restrict__ vc,
    const u16* __restrict__ Wq, const u16* __restrict__ Wk, const u16* __restrict__ Wv,
    const float* __restrict__ bq, const float* __restrict__ bk, const float* __restrict__ bv,
    u16* __restrict__ Qb, u16* __restrict__ Kb, u16* __restrict__ Vtb) {
  __shared__ __align__(16) u16 As[2 * 2 * 8192];
  __shared__ __align__(16) u16 Bs[2 * 2 * 8192];
  const int z = blockIdx.z;
  const u16* A = (z == 0) ? qc : (z == 1) ? kc : vc;
  const u16* W = (z == 0) ? Wq : (z == 1) ? Wk : Wv;
  const float* bias = (z == 0) ? bq : (z == 1) ? bk : bv;
  const int m0 = blockIdx.x * 256, n0 = blockIdx.y * 256;

  floatx4 acc[8][4] = {};
  gemm256_core(A + (size_t)m0 * KK, W + (size_t)n0 * KK, As, Bs, acc);

  const int tid = threadIdx.x;
  const int w = tid >> 6, lane = tid & 63;
  const int lr = lane & 15, lq = lane >> 4;
  const int wm = w >> 2, wn = w & 3;
  const int row0 = m0 + wm * 128;
  const int col0 = n0 + wn * 64;

  if (z == 2) {
    // V^T store [B,H,DK,S]: rr=0..3 are consecutive s -> packed b64
#pragma unroll
    for (int fc = 0; fc < 4; ++fc) {
      const int col = col0 + fc * 16 + lr;
      const float bv_ = bias[col];
      const int h = col >> 6, dk = col & 63;
#pragma unroll
      for (int fr = 0; fr < 8; ++fr) {
        const int row = row0 + fr * 16 + lq * 4;
        const int b = row >> 11, s = row & (SS - 1);
        uint2 pk;
        pk.x = pack2bf(acc[fr][fc][0] + bv_, acc[fr][fc][1] + bv_);
        pk.y = pack2bf(acc[fr][fc][2] + bv_, acc[fr][fc][3] + bv_);
        *(uint2*)&Vtb[(((size_t)(b * HH + h)) * DKK + dk) * SS + s] = pk;
      }
    }
  } else {
    u16* out = (z == 0) ? Qb : Kb;
    const float sc = (z == 0) ? QSCALE : 1.0f;
#pragma unroll
    for (int fc = 0; fc < 4; ++fc) {
      const int col = col0 + fc * 16 + lr;
      const float bv_ = bias[col];
#pragma unroll
      for (int fr = 0; fr < 8; ++fr)
#pragma unroll
        for (int rr = 0; rr < 4; ++rr) {
          const int row = row0 + fr * 16 + lq * 4 + rr;
          out[(size_t)row * NN + col] = f2bf((acc[fr][fc][rr] + bv_) * sc);
        }
    }
  }
}

// ---------------- output GEMM (fp32 store) ----------------
__global__ __launch_bounds__(512, 2) void out_gemm(const u16* __restrict__ A,
                                                   const u16* __restrict__ W,
                                                   const float* __restrict__ bias,
                                                   float* __restrict__ out) {
  __shared__ __align__(16) u16 As[2 * 2 * 8192];
  __shared__ __align__(16) u16 Bs[2 * 2 * 8192];
  const int m0 = blockIdx.x * 256, n0 = blockIdx.y * 256;
  floatx4 acc[8][4] = {};
  gemm256_core(A + (size_t)m0 * KK, W + (size_t)n0 * KK, As, Bs, acc);

  const int tid = threadIdx.x;
  const int w = tid >> 6, lane = tid & 63;
  const int lr = lane & 15, lq = lane >> 4;
  const int wm = w >> 2, wn = w & 3;
  const int row0 = m0 + wm * 128;
  const int col0 = n0 + wn * 64;
#pragma unroll
  for (int fc = 0; fc < 4; ++fc) {
    const int col = col0 + fc * 16 + lr;
    const float bv = bias[col];
#pragma unroll
    for (int fr = 0; fr < 8; ++fr)
#pragma unroll
      for (int rr = 0; rr < 4; ++rr) {
        const int row = row0 + fr * 16 + lq * 4 + rr;
        out[(size_t)row * NN + col] = acc[fr][fc][rr] + bv;
      }
  }
}

// ---------------- flash attention: r4 version (4 blocks/CU) ----------------
__global__ __launch_bounds__(256, 4) void attn_kernel(const u16* __restrict__ Q,
                                                      const u16* __restrict__ Kmat,
                                                      const u16* __restrict__ Vt,
                                                      u16* __restrict__ ctx) {
  __shared__ __align__(16) u16 Ks[64 * 64];  // chunk 2t+half: key 16t+lr, dk 32*half+8lq+j
  __shared__ __align__(16) u16 Vs[64 * 64];  // chunk 2t+half: dk 16t+lr, key 32*half+8lq+j
  __shared__ __align__(16) u16 Ps[4 * PS_REGION];  // per-wave scratch (strips share)
  const int tid = threadIdx.x;
  const int w = tid >> 6, lane = tid & 63;
  const int lr = lane & 15, lq = lane >> 4;
  const int bh = blockIdx.x, b = bh >> 4, h = bh & 15;
  const int q0 = blockIdx.y * 128;

  short8v qf[2][2];
  {
    const u16* qp = Q + ((size_t)(b * SS + q0 + w * 32 + lr)) * DD + h * 64 + lq * 8;
    qf[0][0] = *(const short8v*)qp;
    qf[0][1] = *(const short8v*)(qp + 32);
    qf[1][0] = *(const short8v*)(qp + 16 * DD);
    qf[1][1] = *(const short8v*)(qp + 16 * DD + 32);
  }
  floatx4 o[2][4] = {};
  float l_part[2][4] = {};

  const u16* kp = Kmat + ((size_t)(b * SS + w * 16 + lr)) * DD + h * 64 + lq * 8;
  const u16* vp = Vt + (((size_t)(b * HH + h)) * DKK + w * 16 + lr) * SS + lq * 8;

  for (int kt = 0; kt < SS / 64; ++kt) {
    load_lds16(kp,      &Ks[(2 * w) * 512]);
    load_lds16(kp + 32, &Ks[(2 * w + 1) * 512]);
    load_lds16(vp,      &Vs[(2 * w) * 512]);
    load_lds16(vp + 32, &Vs[(2 * w + 1) * 512]);
    kp += 64 * DD; vp += 64;
    __syncthreads();

    floatx4 sc[2][4] = {};
#pragma unroll
    for (int t = 0; t < 4; ++t) {
      short8v kb0 = *(const short8v*)&Ks[t * 1024 + lane * 8];
      short8v kb1 = *(const short8v*)&Ks[t * 1024 + 512 + lane * 8];
#pragma unroll
      for (int s = 0; s < 2; ++s) {
        sc[s][t] = mfma_k32(qf[s][0], kb0, sc[s][t]);
        sc[s][t] = mfma_k32(qf[s][1], kb1, sc[s][t]);
      }
    }

    short8v pa[2][2];
#pragma unroll
    for (int s = 0; s < 2; ++s) {
#pragma unroll
      for (int t = 0; t < 4; ++t) {
#pragma unroll
        for (int r = 0; r < 4; ++r) {
          const float e = __builtin_amdgcn_exp2f(sc[s][t][r]);
          sc[s][t][r] = e;
          l_part[s][r] += e;
        }
      }
      u16* pw = &Ps[w * PS_REGION];
#pragma unroll
      for (int t = 0; t < 4; ++t) {
        const int base = (2 * t + (lr >> 3)) * PS_CS + (lr & 7);
#pragma unroll
        for (int r = 0; r < 4; ++r)
          pw[base + (lq * 4 + r) * PS_RS] = f2bf(sc[s][t][r]);
      }
      {
        const u16* rp0 = pw + lq * PS_CS + lr * PS_RS;
        const u16* rp1 = pw + (4 + lq) * PS_CS + lr * PS_RS;
        pa[s][0] = cat44(*(const short4v*)rp0, *(const short4v*)(rp0 + 4));
        pa[s][1] = cat44(*(const short4v*)rp1, *(const short4v*)(rp1 + 4));
      }
    }

#pragma unroll
    for (int t = 0; t < 4; ++t) {
      short8v vb0 = *(const short8v*)&Vs[t * 1024 + lane * 8];
      short8v vb1 = *(const short8v*)&Vs[t * 1024 + 512 + lane * 8];
#pragma unroll
      for (int s = 0; s < 2; ++s) {
        o[s][t] = mfma_k32(pa[s][0], vb0, o[s][t]);
        o[s][t] = mfma_k32(pa[s][1], vb1, o[s][t]);
      }
    }
    __syncthreads();
  }

  float inv[2][4];
#pragma unroll
  for (int s = 0; s < 2; ++s)
#pragma unroll
    for (int r = 0; r < 4; ++r) {
      float l = l_part[s][r];
      l += __shfl_xor(l, 1); l += __shfl_xor(l, 2);
      l += __shfl_xor(l, 4); l += __shfl_xor(l, 8);
      inv[s][r] = 1.0f / l;
    }

#pragma unroll
  for (int s = 0; s < 2; ++s)
#pragma unroll
    for (int r = 0; r < 4; ++r) {
      const int sq = q0 + w * 32 + s * 16 + lq * 4 + r;
      u16* cp = ctx + ((size_t)(b * SS + sq)) * DD + h * 64;
      const float iv = inv[s][r];
#pragma unroll
      for (int t = 0; t < 4; ++t)
        cp[t * 16 + lr] = f2bf(o[s][t][r] * iv);
    }
}

// ---------------- launch ----------------
extern "C" void kernel_launch(void* const* d_in, const int* in_sizes, int n_in,
                              void* d_out, int out_size, void* d_ws, size_t ws_size,
                              hipStream_t stream) {
  const float* query = (const float*)d_in[0];
  const float* key   = (const float*)d_in[1];
  const float* value = (const float*)d_in[2];
  const float* Wq = (const float*)d_in[3];  const float* bq = (const float*)d_in[4];
  const float* Wk = (const float*)d_in[5];  const float* bk = (const float*)d_in[6];
  const float* Wv = (const float*)d_in[7];  const float* bv = (const float*)d_in[8];
  const float* Wo = (const float*)d_in[9];  const float* bo = (const float*)d_in[10];
  float* out = (float*)d_out;

  char* ws = (char*)d_ws;
  size_t off = 0;
  u16* Wb   = (u16*)(ws + off); off += (size_t)4 * DD * DD * 2;  // Wq,Wk,Wv,Wo bf16
  u16* Qb   = (u16*)(ws + off); off += (size_t)MM * DD * 2;      // scaled Q [B,S,D]
  u16* Kb   = (u16*)(ws + off); off += (size_t)MM * DD * 2;      // [B,S,D]
  u16* Vtb  = (u16*)(ws + off); off += (size_t)MM * DD * 2;      // [B,H,DK,S]
  u16* qc   = (u16*)(ws + off);
  u16* ctxb = qc;               off += (size_t)MM * DD * 2;      // ctx aliases qc
  u16* kc = (u16*)d_out;                       // scratch in d_out (overwritten last)
  u16* vc = (u16*)d_out + (size_t)MM * DD;
  u16* Wq_b = Wb, *Wk_b = Wb + (size_t)DD * DD, *Wv_b = Wb + (size_t)2 * DD * DD,
     *Wo_b = Wb + (size_t)3 * DD * DD;

  const int wn = DD * DD, an = MM * DD;
  cvt_w4<<<dim3(wn / 2048, 4), 256, 0, stream>>>(Wq, Wk, Wv, Wo, Wb);
  cvt_a3<<<dim3(an / 2048, 3), 256, 0, stream>>>(query, key, value, qc, kc, vc);

  proj_gemm<<<dim3(MM / 256, NN / 256, 3), 512, 0, stream>>>(
      qc, kc, vc, Wq_b, Wk_b, Wv_b, bq, bk, bv, Qb, Kb, Vtb);

  attn_kernel<<<dim3(BB * HH, SS / 128), 256, 0, stream>>>(Qb, Kb, Vtb, ctxb);

  out_gemm<<<dim3(MM / 256, NN / 256), 512, 0, stream>>>(ctxb, Wo_b, bo, out);
}

// Round 3
// 342.088 us; speedup vs baseline: 1.2372x; 1.0617x over previous
//
#include <hip/hip_runtime.h>

typedef unsigned short u16;
typedef unsigned int u32;
typedef __attribute__((ext_vector_type(8))) short short8v;
typedef __attribute__((ext_vector_type(4))) short short4v;
typedef __attribute__((ext_vector_type(4))) float floatx4;

#define BB 4
#define SS 2048
#define DD 1024
#define HH 16
#define DKK 64
#define MM (BB * SS)   // 8192
#define KK DD
#define NN DD
// log2(e)/sqrt(DK): folded into Q projection so scores feed exp2 directly
#define QSCALE 0.18033688011112042f

// Ps padded layout (r3-verified conflict-free): row stride 12 u16, chunk stride 200 u16
#define PS_RS 12
#define PS_CS 200
#define PS_REGION 1600

__device__ __forceinline__ u16 f2bf(float f) {
  union { __bf16 h; u16 u; } r; r.h = (__bf16)f; return r.u;
}
__device__ __forceinline__ u32 pack2bf(float a, float b) {
  union { u32 u; __bf16 h[2]; } r;
  r.h[0] = (__bf16)a; r.h[1] = (__bf16)b; return r.u;
}
__device__ __forceinline__ short8v cat44(short4v a, short4v b) {
  return __builtin_shufflevector(a, b, 0, 1, 2, 3, 4, 5, 6, 7);
}

__device__ __forceinline__ void load_lds16(const void* g, void* l) {
  __builtin_amdgcn_global_load_lds((const __attribute__((address_space(1))) void*)g,
                                   (__attribute__((address_space(3))) void*)l, 16, 0, 0);
}

__device__ __forceinline__ floatx4 mfma_k32(short8v a, short8v b, floatx4 c) {
  return __builtin_amdgcn_mfma_f32_16x16x32_bf16(a, b, c, 0, 0, 0);
}

// ---------------- fp32 -> bf16 converts (fused launches) ----------------
__global__ __launch_bounds__(256) void cvt_w4(const float* __restrict__ w0,
                                              const float* __restrict__ w1,
                                              const float* __restrict__ w2,
                                              const float* __restrict__ w3,
                                              u16* __restrict__ out) {
  const int y = blockIdx.y;
  const float* in = (y == 0) ? w0 : (y == 1) ? w1 : (y == 2) ? w2 : w3;
  u16* o = out + (size_t)y * DD * DD;
  const int i = (blockIdx.x * 256 + threadIdx.x) * 8;
  float4 a = *(const float4*)(in + i);
  float4 b = *(const float4*)(in + i + 4);
  uint4 v;
  v.x = pack2bf(a.x, a.y); v.y = pack2bf(a.z, a.w);
  v.z = pack2bf(b.x, b.y); v.w = pack2bf(b.z, b.w);
  *(uint4*)(o + i) = v;
}

__global__ __launch_bounds__(256) void cvt_a3(const float* __restrict__ a0,
                                              const float* __restrict__ a1,
                                              const float* __restrict__ a2,
                                              u16* __restrict__ o0, u16* __restrict__ o1,
                                              u16* __restrict__ o2) {
  const int y = blockIdx.y;
  const float* in = (y == 0) ? a0 : (y == 1) ? a1 : a2;
  u16* o = (y == 0) ? o0 : (y == 1) ? o1 : o2;
  const int i = (blockIdx.x * 256 + threadIdx.x) * 8;
  float4 a = *(const float4*)(in + i);
  float4 b = *(const float4*)(in + i + 4);
  uint4 v;
  v.x = pack2bf(a.x, a.y); v.y = pack2bf(a.z, a.w);
  v.z = pack2bf(b.x, b.y); v.w = pack2bf(b.z, b.w);
  *(uint4*)(o + i) = v;
}

// ================= 256x256 8-phase GEMM core (T2+T3+T4+T5) =================
// BM=BN=256, BK=64, 2 K-tiles/iteration, 8 waves (2M x 4N), per-wave 128x64.
// LDS: As/Bs each [2 dbuf][2 half][128 rows][64 k] bf16 = 64 KiB -> 128 KiB total.
// Swizzle (T2): element (r,c) stored at c' = c ^ ((r&7)<<3). 16B-group-granular,
// so global_load_lds keeps a LINEAR LDS dest and the SOURCE 16B-group is
// pre-swizzled per lane (rule #21). ds_read of a frag column then spreads the
// 16 rows across 8 distinct 16B slots -> 2-way bank aliasing (free).
// Schedule (ledger-derived; counted waits, never drain-0 in steady state):
//   iter j consumes tile e=2j (dbuf0, phases 0-3) and o=2j+1 (dbuf1, phases 4-7).
//   stages: p0:A0(o) p1:A1(o) p2:B0(e+2) p3:B1(e+2) p4:A0(e+2) p5:A1(e+2)
//           p6:B0(o+2) p7:B1(o+2)   (each 2 x global_load_lds per thread)
//   waits: vmcnt(4) at p3 and p7 (2 half-tiles in flight). Last iter p3: vmcnt(0).
#define NT (KK / 64)     // 16 K-tiles
#define ITERS (NT / 2)   // 8

__device__ __forceinline__ void stage_half(const u16* __restrict__ gsrc, u16* ldst,
                                           int tid) {
#pragma unroll
  for (int L = 0; L < 2; ++L) {
    const int s = L * 512 + tid;
    const int r = s >> 3;
    const int g = (s & 7) ^ (r & 7);   // inverse-swizzled source 16B-group
    load_lds16(gsrc + (size_t)r * KK + g * 8, ldst + s * 8);
  }
}

__device__ __forceinline__ void gemm256_core(const u16* __restrict__ A,  // + m0*KK
                                             const u16* __restrict__ W,  // + n0*KK
                                             u16* As, u16* Bs,           // [2][2][8192]
                                             floatx4 (&acc)[8][4]) {
  const int tid = threadIdx.x;
  const int w = tid >> 6, lane = tid & 63;
  const int wm = w >> 2, wn = w & 3;
  const int wnh = wn >> 1, wno = wn & 1;
  const int lr = lane & 15;
  // swizzled col base for kk=0; kk=1 flips bit5 (c0 ^ 32)
  const int c0 = (((lane >> 2) & 1) << 5) | ((((lane >> 4) ^ lane) & 3) << 3);

#define AP(d, fr, kk) \
  (*(const short8v*)(As + ((d)*2 + wm) * 8192 + ((fr)*16 + lr) * 64 + (c0 ^ ((kk)*32))))
#define BP(d, fc, kk) \
  (*(const short8v*)(Bs + ((d)*2 + wnh) * 8192 + (wno * 64 + (fc)*16 + lr) * 64 + (c0 ^ ((kk)*32))))
#define MFMA8(FROFF, B, FCOFF)                                                  \
  _Pragma("unroll") for (int fr_ = 0; fr_ < 4; ++fr_)                           \
  _Pragma("unroll") for (int fc_ = 0; fc_ < 2; ++fc_) {                         \
    acc[(FROFF) + fr_][(FCOFF) + fc_] =                                         \
        mfma_k32(a[fr_][0], B[fc_][0], acc[(FROFF) + fr_][(FCOFF) + fc_]);      \
    acc[(FROFF) + fr_][(FCOFF) + fc_] =                                         \
        mfma_k32(a[fr_][1], B[fc_][1], acc[(FROFF) + fr_][(FCOFF) + fc_]);      \
  }
#define BAR() __builtin_amdgcn_s_barrier()
#define PRIO1() __builtin_amdgcn_s_setprio(1)
#define PRIO0() __builtin_amdgcn_s_setprio(0)

  short8v a[4][2], b01[2][2], b23[2][2];

  // prologue: tile0 all 4 halves + tile1 B-halves; wait first 4 halves landed
  stage_half(A, As + 0 * 8192, tid);
  stage_half(A + (size_t)128 * KK, As + 1 * 8192, tid);
  stage_half(W, Bs + 0 * 8192, tid);
  stage_half(W + (size_t)128 * KK, Bs + 1 * 8192, tid);
  stage_half(W + 64, Bs + 2 * 8192, tid);
  stage_half(W + (size_t)128 * KK + 64, Bs + 3 * 8192, tid);
  asm volatile("s_waitcnt vmcnt(4)" ::: "memory");
  BAR();

#pragma unroll 1
  for (int j = 0; j < ITERS; ++j) {
    const int e = 2 * j, o = e + 1;
    const bool haveE2 = (j + 1 < ITERS);
    // ---- phase 0: tile e reads A fr0-3 + B fc0-1; stage A0(o) -> d1 H0
#pragma unroll
    for (int fr = 0; fr < 4; ++fr) { a[fr][0] = AP(0, fr, 0); a[fr][1] = AP(0, fr, 1); }
#pragma unroll
    for (int fc = 0; fc < 2; ++fc) { b01[fc][0] = BP(0, fc, 0); b01[fc][1] = BP(0, fc, 1); }
    stage_half(A + (size_t)o * 64, As + 2 * 8192, tid);
    BAR(); PRIO1(); MFMA8(0, b01, 0); PRIO0(); BAR();
    // ---- phase 1: reads B fc2-3; stage A1(o) -> d1 H1
#pragma unroll
    for (int fc = 0; fc < 2; ++fc) { b23[fc][0] = BP(0, fc + 2, 0); b23[fc][1] = BP(0, fc + 2, 1); }
    stage_half(A + (size_t)128 * KK + (size_t)o * 64, As + 3 * 8192, tid);
    BAR(); PRIO1(); MFMA8(0, b23, 2); PRIO0(); BAR();
    // ---- phase 2: reads A fr4-7; stage B0(e+2) -> d0 H0
#pragma unroll
    for (int fr = 0; fr < 4; ++fr) { a[fr][0] = AP(0, fr + 4, 0); a[fr][1] = AP(0, fr + 4, 1); }
    if (haveE2) stage_half(W + (size_t)(e + 2) * 64, Bs + 0 * 8192, tid);
    BAR(); PRIO1(); MFMA8(4, b01, 0); PRIO0(); BAR();
    // ---- phase 3: stage B1(e+2) -> d0 H1; counted wait
    if (haveE2) {
      stage_half(W + (size_t)128 * KK + (size_t)(e + 2) * 64, Bs + 1 * 8192, tid);
      asm volatile("s_waitcnt vmcnt(4)" ::: "memory");
    } else {
      asm volatile("s_waitcnt vmcnt(0)" ::: "memory");
    }
    BAR(); PRIO1(); MFMA8(4, b23, 2); PRIO0(); BAR();
    // ---- phase 4: tile o reads A fr0-3 + B fc0-1 (d1); stage A0(e+2) -> d0 H0
#pragma unroll
    for (int fr = 0; fr < 4; ++fr) { a[fr][0] = AP(1, fr, 0); a[fr][1] = AP(1, fr, 1); }
#pragma unroll
    for (int fc = 0; fc < 2; ++fc) { b01[fc][0] = BP(1, fc, 0); b01[fc][1] = BP(1, fc, 1); }
    if (haveE2) stage_half(A + (size_t)(e + 2) * 64, As + 0 * 8192, tid);
    BAR(); PRIO1(); MFMA8(0, b01, 0); PRIO0(); BAR();
    // ---- phase 5: reads B fc2-3 (d1); stage A1(e+2) -> d0 H1
#pragma unroll
    for (int fc = 0; fc < 2; ++fc) { b23[fc][0] = BP(1, fc + 2, 0); b23[fc][1] = BP(1, fc + 2, 1); }
    if (haveE2) stage_half(A + (size_t)128 * KK + (size_t)(e + 2) * 64, As + 1 * 8192, tid);
    BAR(); PRIO1(); MFMA8(0, b23, 2); PRIO0(); BAR();
    // ---- phase 6: reads A fr4-7 (d1); stage B0(o+2) -> d1 H0
#pragma unroll
    for (int fr = 0; fr < 4; ++fr) { a[fr][0] = AP(1, fr + 4, 0); a[fr][1] = AP(1, fr + 4, 1); }
    if (haveE2) stage_half(W + (size_t)(o + 2) * 64, Bs + 2 * 8192, tid);
    BAR(); PRIO1(); MFMA8(4, b01, 0); PRIO0(); BAR();
    // ---- phase 7: stage B1(o+2) -> d1 H1; counted wait (skip entirely on last)
    if (haveE2) {
      stage_half(W + (size_t)128 * KK + (size_t)(o + 2) * 64, Bs + 3 * 8192, tid);
      asm volatile("s_waitcnt vmcnt(4)" ::: "memory");
    }
    BAR(); PRIO1(); MFMA8(4, b23, 2); PRIO0(); BAR();
  }
#undef AP
#undef BP
#undef MFMA8
#undef BAR
#undef PRIO1
#undef PRIO0
}

// ---------------- fused QKV projection (blockIdx.z selects q/k/v) ----------------
__global__ __launch_bounds__(512, 2) void proj_gemm(
    const u16* __restrict__ qc, const u16* __restrict__ kc, const u16* __restrict__ vc,
    const u16* __restrict__ Wq, const u16* __restrict__ Wk, const u16* __restrict__ Wv,
    const float* __restrict__ bq, const float* __restrict__ bk, const float* __restrict__ bv,
    u16* __restrict__ Qb, u16* __restrict__ Kb, u16* __restrict__ Vtb) {
  __shared__ __align__(16) u16 As[2 * 2 * 8192];
  __shared__ __align__(16) u16 Bs[2 * 2 * 8192];
  const int z = blockIdx.z;
  const u16* A = (z == 0) ? qc : (z == 1) ? kc : vc;
  const u16* W = (z == 0) ? Wq : (z == 1) ? Wk : Wv;
  const float* bias = (z == 0) ? bq : (z == 1) ? bk : bv;
  const int m0 = blockIdx.x * 256, n0 = blockIdx.y * 256;

  floatx4 acc[8][4] = {};
  gemm256_core(A + (size_t)m0 * KK, W + (size_t)n0 * KK, As, Bs, acc);

  const int tid = threadIdx.x;
  const int w = tid >> 6, lane = tid & 63;
  const int lr = lane & 15, lq = lane >> 4;
  const int wm = w >> 2, wn = w & 3;
  const int row0 = m0 + wm * 128;
  const int col0 = n0 + wn * 64;

  if (z == 2) {
    // V^T store [B,H,DK,S]: rr=0..3 are consecutive s -> packed b64
#pragma unroll
    for (int fc = 0; fc < 4; ++fc) {
      const int col = col0 + fc * 16 + lr;
      const float bv_ = bias[col];
      const int h = col >> 6, dk = col & 63;
#pragma unroll
      for (int fr = 0; fr < 8; ++fr) {
        const int row = row0 + fr * 16 + lq * 4;
        const int b = row >> 11, s = row & (SS - 1);
        uint2 pk;
        pk.x = pack2bf(acc[fr][fc][0] + bv_, acc[fr][fc][1] + bv_);
        pk.y = pack2bf(acc[fr][fc][2] + bv_, acc[fr][fc][3] + bv_);
        *(uint2*)&Vtb[(((size_t)(b * HH + h)) * DKK + dk) * SS + s] = pk;
      }
    }
  } else {
    u16* out = (z == 0) ? Qb : Kb;
    const float sc = (z == 0) ? QSCALE : 1.0f;
#pragma unroll
    for (int fc = 0; fc < 4; ++fc) {
      const int col = col0 + fc * 16 + lr;
      const float bv_ = bias[col];
#pragma unroll
      for (int fr = 0; fr < 8; ++fr)
#pragma unroll
        for (int rr = 0; rr < 4; ++rr) {
          const int row = row0 + fr * 16 + lq * 4 + rr;
          out[(size_t)row * NN + col] = f2bf((acc[fr][fc][rr] + bv_) * sc);
        }
    }
  }
}

// ---------------- output GEMM (fp32 store) ----------------
__global__ __launch_bounds__(512, 2) void out_gemm(const u16* __restrict__ A,
                                                   const u16* __restrict__ W,
                                                   const float* __restrict__ bias,
                                                   float* __restrict__ out) {
  __shared__ __align__(16) u16 As[2 * 2 * 8192];
  __shared__ __align__(16) u16 Bs[2 * 2 * 8192];
  const int m0 = blockIdx.x * 256, n0 = blockIdx.y * 256;
  floatx4 acc[8][4] = {};
  gemm256_core(A + (size_t)m0 * KK, W + (size_t)n0 * KK, As, Bs, acc);

  const int tid = threadIdx.x;
  const int w = tid >> 6, lane = tid & 63;
  const int lr = lane & 15, lq = lane >> 4;
  const int wm = w >> 2, wn = w & 3;
  const int row0 = m0 + wm * 128;
  const int col0 = n0 + wn * 64;
#pragma unroll
  for (int fc = 0; fc < 4; ++fc) {
    const int col = col0 + fc * 16 + lr;
    const float bv = bias[col];
#pragma unroll
    for (int fr = 0; fr < 8; ++fr)
#pragma unroll
      for (int rr = 0; rr < 4; ++rr) {
        const int row = row0 + fr * 16 + lq * 4 + rr;
        out[(size_t)row * NN + col] = acc[fr][fc][rr] + bv;
      }
  }
}

// ---------------- flash attention: r6 = Ks-dbuf + counted vmcnt pipeline ----------------
// r6: single-buffered staging exposed ~300-500cy global->LDS latency at every one of
// 32 iterations (both __syncthreads drain vmcnt(0) right after the loads issue).
// New schedule: Ks double-buffered (full-iteration cover), Vs single-buffered
// (covered by QK+softmax phase), 3 raw barriers/iter with COUNTED vmcnt:
//   iter kt: B0 (closes PV(kt-1) reads of Vs)
//            issue Vs(kt) [2], issue Ks(kt+1)->K[b^1] [2]
//            vmcnt(4) [last iter: 2]  -> Ks(kt) landed;  B1
//            QK(K[b]) + softmax/Ps
//            vmcnt(2) [last iter: 0]  -> Vs(kt) landed;  B2
//            PV(Vs)
// Hazard ledger: Vs overwrite is 1 barrier (B0) after PV(kt-1) reads; K[b^1]
// overwrite is 2 barriers after QK(kt-1) reads; all counted waits proven by
// issue-order arithmetic (see W1/W2 comments). LDS 16384+8192+12800=37376 B
// -> still 4 blocks/CU. T5 setprio wraps both MFMA clusters.
__global__ __launch_bounds__(256, 4) void attn_kernel(const u16* __restrict__ Q,
                                                      const u16* __restrict__ Kmat,
                                                      const u16* __restrict__ Vt,
                                                      u16* __restrict__ ctx) {
  __shared__ __align__(16) u16 Ks[2][64 * 64];  // dbuf; chunk 2t+half: key 16t+lr, dk 32*half+8lq+j
  __shared__ __align__(16) u16 Vs[64 * 64];     // chunk 2t+half: dk 16t+lr, key 32*half+8lq+j
  __shared__ __align__(16) u16 Ps[4 * PS_REGION];  // per-wave scratch (strips share)
  const int tid = threadIdx.x;
  const int w = tid >> 6, lane = tid & 63;
  const int lr = lane & 15, lq = lane >> 4;
  const int bh = blockIdx.x, b = bh >> 4, h = bh & 15;
  const int q0 = blockIdx.y * 128;

  short8v qf[2][2];
  {
    const u16* qp = Q + ((size_t)(b * SS + q0 + w * 32 + lr)) * DD + h * 64 + lq * 8;
    qf[0][0] = *(const short8v*)qp;
    qf[0][1] = *(const short8v*)(qp + 32);
    qf[1][0] = *(const short8v*)(qp + 16 * DD);
    qf[1][1] = *(const short8v*)(qp + 16 * DD + 32);
  }
  floatx4 o[2][4] = {};
  float l_part[2][4] = {};

  const u16* kp = Kmat + ((size_t)(b * SS + w * 16 + lr)) * DD + h * 64 + lq * 8;
  const u16* vp = Vt + (((size_t)(b * HH + h)) * DKK + w * 16 + lr) * SS + lq * 8;

  // prologue: stage Ks(0) -> K[0]
  load_lds16(kp,      &Ks[0][(2 * w) * 512]);
  load_lds16(kp + 32, &Ks[0][(2 * w + 1) * 512]);
  kp += 64 * DD;

#pragma unroll 1
  for (int kt = 0; kt < SS / 64; ++kt) {
    const int bf = kt & 1;
    const bool haveNext = (kt + 1 < SS / 64);
    __builtin_amdgcn_s_barrier();  // B0: all PV(kt-1) reads of Vs done (no-op kt=0)
    // issue Vs(kt) [2 loads]
    load_lds16(vp,      &Vs[(2 * w) * 512]);
    load_lds16(vp + 32, &Vs[(2 * w + 1) * 512]);
    vp += 64;
    if (haveNext) {
      // issue Ks(kt+1) -> K[bf^1] [2 loads]; last reads of K[bf^1] were in
      // QK(kt-1), two barriers ago.
      load_lds16(kp,      &Ks[bf ^ 1][(2 * w) * 512]);
      load_lds16(kp + 32, &Ks[bf ^ 1][(2 * w + 1) * 512]);
      kp += 64 * DD;
      // W1: outstanding <= [Ks(kt) 2, Vs(kt) 2, Ks(kt+1) 2] -> vmcnt(4) lands Ks(kt)
      asm volatile("s_waitcnt vmcnt(4)" ::: "memory");
    } else {
      // W1(last): outstanding <= [Ks(kt) 2, Vs(kt) 2] -> vmcnt(2) lands Ks(kt)
      asm volatile("s_waitcnt vmcnt(2)" ::: "memory");
    }
    __builtin_amdgcn_s_barrier();  // B1: Ks(kt) landed in all waves

    // S: D[row=q(4lq+r)][col=key(16t+lr)] per strip
    floatx4 sc[2][4] = {};
    __builtin_amdgcn_s_setprio(1);
#pragma unroll
    for (int t = 0; t < 4; ++t) {
      short8v kb0 = *(const short8v*)&Ks[bf][t * 1024 + lane * 8];
      short8v kb1 = *(const short8v*)&Ks[bf][t * 1024 + 512 + lane * 8];
#pragma unroll
      for (int s = 0; s < 2; ++s) {
        sc[s][t] = mfma_k32(qf[s][0], kb0, sc[s][t]);
        sc[s][t] = mfma_k32(qf[s][1], kb1, sc[s][t]);
      }
    }
    __builtin_amdgcn_s_setprio(0);

    short8v pa[2][2];
#pragma unroll
    for (int s = 0; s < 2; ++s) {
#pragma unroll
      for (int t = 0; t < 4; ++t) {
#pragma unroll
        for (int r = 0; r < 4; ++r) {
          const float e = __builtin_amdgcn_exp2f(sc[s][t][r]);
          sc[s][t][r] = e;
          l_part[s][r] += e;
        }
      }
      u16* pw = &Ps[w * PS_REGION];
#pragma unroll
      for (int t = 0; t < 4; ++t) {
        const int base = (2 * t + (lr >> 3)) * PS_CS + (lr & 7);
#pragma unroll
        for (int r = 0; r < 4; ++r)
          pw[base + (lq * 4 + r) * PS_RS] = f2bf(sc[s][t][r]);
      }
      {
        const u16* rp0 = pw + lq * PS_CS + lr * PS_RS;
        const u16* rp1 = pw + (4 + lq) * PS_CS + lr * PS_RS;
        pa[s][0] = cat44(*(const short4v*)rp0, *(const short4v*)(rp0 + 4));
        pa[s][1] = cat44(*(const short4v*)rp1, *(const short4v*)(rp1 + 4));
      }
    }

    if (haveNext) {
      // W2: outstanding <= [Vs(kt) 2, Ks(kt+1) 2] -> vmcnt(2) lands Vs(kt)
      asm volatile("s_waitcnt vmcnt(2)" ::: "memory");
    } else {
      asm volatile("s_waitcnt vmcnt(0)" ::: "memory");
    }
    __builtin_amdgcn_s_barrier();  // B2: Vs(kt) landed in all waves

    __builtin_amdgcn_s_setprio(1);
#pragma unroll
    for (int t = 0; t < 4; ++t) {
      short8v vb0 = *(const short8v*)&Vs[t * 1024 + lane * 8];
      short8v vb1 = *(const short8v*)&Vs[t * 1024 + 512 + lane * 8];
#pragma unroll
      for (int s = 0; s < 2; ++s) {
        o[s][t] = mfma_k32(pa[s][0], vb0, o[s][t]);
        o[s][t] = mfma_k32(pa[s][1], vb1, o[s][t]);
      }
    }
    __builtin_amdgcn_s_setprio(0);
  }

  float inv[2][4];
#pragma unroll
  for (int s = 0; s < 2; ++s)
#pragma unroll
    for (int r = 0; r < 4; ++r) {
      float l = l_part[s][r];
      l += __shfl_xor(l, 1); l += __shfl_xor(l, 2);
      l += __shfl_xor(l, 4); l += __shfl_xor(l, 8);
      inv[s][r] = 1.0f / l;
    }

#pragma unroll
  for (int s = 0; s < 2; ++s)
#pragma unroll
    for (int r = 0; r < 4; ++r) {
      const int sq = q0 + w * 32 + s * 16 + lq * 4 + r;
      u16* cp = ctx + ((size_t)(b * SS + sq)) * DD + h * 64;
      const float iv = inv[s][r];
#pragma unroll
      for (int t = 0; t < 4; ++t)
        cp[t * 16 + lr] = f2bf(o[s][t][r] * iv);
    }
}

// ---------------- launch ----------------
extern "C" void kernel_launch(void* const* d_in, const int* in_sizes, int n_in,
                              void* d_out, int out_size, void* d_ws, size_t ws_size,
                              hipStream_t stream) {
  const float* query = (const float*)d_in[0];
  const float* key   = (const float*)d_in[1];
  const float* value = (const float*)d_in[2];
  const float* Wq = (const float*)d_in[3];  const float* bq = (const float*)d_in[4];
  const float* Wk = (const float*)d_in[5];  const float* bk = (const float*)d_in[6];
  const float* Wv = (const float*)d_in[7];  const float* bv = (const float*)d_in[8];
  const float* Wo = (const float*)d_in[9];  const float* bo = (const float*)d_in[10];
  float* out = (float*)d_out;

  char* ws = (char*)d_ws;
  size_t off = 0;
  u16* Wb   = (u16*)(ws + off); off += (size_t)4 * DD * DD * 2;  // Wq,Wk,Wv,Wo bf16
  u16* Qb   = (u16*)(ws + off); off += (size_t)MM * DD * 2;      // scaled Q [B,S,D]
  u16* Kb   = (u16*)(ws + off); off += (size_t)MM * DD * 2;      // [B,S,D]
  u16* Vtb  = (u16*)(ws + off); off += (size_t)MM * DD * 2;      // [B,H,DK,S]
  u16* qc   = (u16*)(ws + off);
  u16* ctxb = qc;               off += (size_t)MM * DD * 2;      // ctx aliases qc
  u16* kc = (u16*)d_out;                       // scratch in d_out (overwritten last)
  u16* vc = (u16*)d_out + (size_t)MM * DD;
  u16* Wq_b = Wb, *Wk_b = Wb + (size_t)DD * DD, *Wv_b = Wb + (size_t)2 * DD * DD,
     *Wo_b = Wb + (size_t)3 * DD * DD;

  const int wn = DD * DD, an = MM * DD;
  cvt_w4<<<dim3(wn / 2048, 4), 256, 0, stream>>>(Wq, Wk, Wv, Wo, Wb);
  cvt_a3<<<dim3(an / 2048, 3), 256, 0, stream>>>(query, key, value, qc, kc, vc);

  proj_gemm<<<dim3(MM / 256, NN / 256, 3), 512, 0, stream>>>(
      qc, kc, vc, Wq_b, Wk_b, Wv_b, bq, bk, bv, Qb, Kb, Vtb);

  attn_kernel<<<dim3(BB * HH, SS / 128), 256, 0, stream>>>(Qb, Kb, Vtb, ctxb);

  out_gemm<<<dim3(MM / 256, NN / 256), 512, 0, stream>>>(ctxb, Wo_b, bo, out);
}